// Round 10
// baseline (141.636 us; speedup 1.0000x reference)
//
#include <hip/hip_runtime.h>
#include <cmath>

namespace {
constexpr int T = 1024, BATCH = 128, U = 100, E = 100, P = 20, C = 2;
constexpr int TC = 64, NC = 16;          // chunk size, number of chunks
constexpr float DT = 0.001f, SCALE = 0.2f, MU = 1.0f;
constexpr float DTS = DT * SCALE;

// ---- LDS arena ----
// WL [100 j][464 B]   f16 w1, k'-interleaved (k'=2k | 2(k-U)+1), pads [400,464)=0
// ZB [2][64 t][464 B] f16 z (x_j,y_j)@4j, pads zero           (MFMA A operand)
// EB [2][64 t][208 B] f16 u, t-major rows (coalesced gather writeback)
// HB [2][100 j][128 B] f16 h1, [unit][time] rows, chunk-XOR-swizzled
// XA [1024] int tokens (whole sequence, loaded once)
constexpr uint32_t WROW = 464u, ZROW = 464u, EROW = 208u, HROW = 128u;
constexpr uint32_t WLB = 0u;
constexpr uint32_t ZBB = 46400u, ZBUF = 29696u;
constexpr uint32_t EBB = 105792u, EBUF = 13312u;
constexpr uint32_t HBB = 132416u, HBUF = 12800u;
constexpr uint32_t XAB = 158016u;
constexpr uint32_t ARENA = 162112u;      // <= 163840

typedef _Float16 f16x8 __attribute__((ext_vector_type(8)));
typedef _Float16 f16x4 __attribute__((ext_vector_type(4)));
typedef float f32x16 __attribute__((ext_vector_type(16)));
typedef float f32x2 __attribute__((ext_vector_type(2)));
typedef _Float16 h2_t __attribute__((ext_vector_type(2)));

// packed Euler bank: 5 substeps, (x,y) in one f32x2, v_pk_fma for the vector ops.
__device__ __forceinline__ void eul5p(f32x2& v, float dom, float ax) {
    constexpr float c0 = 1.0f + DT * MU;
    const f32x2 dd = {-dom, dom};
    const f32x2 aa = {ax, 0.f};
#pragma unroll
    for (int s = 0; s < 5; ++s) {
        float r2 = fmaf(v[1], v[1], v[0] * v[0]);
        float sc = fmaf(-DT, r2, c0);
        f32x2 vyx = __builtin_shufflevector(v, v, 1, 0);
        f32x2 w = __builtin_elementwise_fma(vyx, dd, aa);
        f32x2 scv = {sc, sc};
        v = __builtin_elementwise_fma(v, scv, w);
    }
}

__device__ __forceinline__ h2_t cvt2h(float a, float b) {
    auto r = __builtin_amdgcn_cvt_pkrtz(a, b);
    return __builtin_bit_cast(h2_t, r);
}

__launch_bounds__(512, 1)
__global__ void donn_kernel(const int* __restrict__ xg,
                            const float* __restrict__ emb,
                            const float* __restrict__ omega1,
                            const float* __restrict__ omega2,
                            const float* __restrict__ w1,
                            const float* __restrict__ b1,
                            const float* __restrict__ w2,
                            const float* __restrict__ b2,
                            const float* __restrict__ wp,
                            const float* __restrict__ bp,
                            const float* __restrict__ wh,
                            const float* __restrict__ bh,
                            float* __restrict__ out)
{
    const int b = blockIdx.x;
    const int tid = threadIdx.x;

    __shared__ __align__(16) char smem[ARENA];
    int* xa = (int*)(smem + XAB);

    // ---- per-role persistent state ----
    f32x2 v1 = {0.f, 0.f}, v2 = {0.f, 0.f};
    float dom1 = 0.f, dom2 = 0.f;
    int jc = 0, j2c = 0;
    bool act1 = false;
    int lane = 0, mh = 0, np = 0, mw = 0;
    float b1r[2] = {0.f, 0.f};
    uint32_t brow[2] = {0u, 0u};

    if (tid < 128) {                       // osc1: unit j = tid (j<100 active)
        jc = (tid < U) ? tid : (U - 1);
        act1 = tid < U;
        dom1 = DT * omega1[jc];
    } else if (tid < 256) {                // osc2: unit j = tid-128
        const int j2 = tid - 128;
        j2c = (j2 < U) ? j2 : (U - 1);
        dom2 = DT * omega2[j2c];
    } else {                               // mm: 4 waves, 32x32x16 MFMA + gather
        mw = (tid >> 6) - 4;               // 0..3
        lane = tid & 63;
        mh = mw >> 1;                      // t-half: rows [mh*32, mh*32+32)
        np = mw & 1;                       // n-pair: j = np*64 + nt*32 + (lane&31)
#pragma unroll
        for (int nt = 0; nt < 2; ++nt) {
            int j = np * 64 + nt * 32 + (lane & 31);
            int jj = (j < U) ? j : (U - 1);
            b1r[nt] = b1[jj];
            brow[nt] = WLB + (uint32_t)jj * WROW + 16u * (uint32_t)(lane >> 5);
        }
    }

    // ---- prologue ----
    for (int i = tid; i < T; i += 512) xa[i] = xg[b * T + i];   // whole token seq
    for (int idx = tid; idx < 200 * 100; idx += 512) {          // w1 -> WL
        int k = idx / 100, j = idx - 100 * k;
        int kp = (k < U) ? (2 * k) : (2 * (k - U) + 1);
        *(_Float16*)(smem + WLB + (uint32_t)j * WROW + 2u * (uint32_t)kp) = (_Float16)w1[k * U + j];
    }
    for (int idx = tid; idx < 100 * 16; idx += 512) {           // WL pads [400,464)
        int row = idx >> 4, wd = idx & 15;
        *(float*)(smem + WLB + (uint32_t)row * WROW + 400u + 4u * (uint32_t)wd) = 0.f;
    }
    for (int idx = tid; idx < 128 * 16; idx += 512) {           // ZB pads [400,464)
        int zr = idx >> 4, wd = idx & 15;
        uint32_t base = ZBB + (uint32_t)(zr >> 6) * ZBUF + (uint32_t)(zr & 63) * ZROW;
        *(float*)(smem + base + 400u + 4u * (uint32_t)wd) = 0.f;
    }
    __syncthreads();
    for (int idx = tid; idx < TC * E; idx += 512) {             // EB[0] = chunk 0
        int t = idx / 100, j = idx - 100 * t;
        int tok = xa[t];
        *(_Float16*)(smem + EBB + (uint32_t)t * EROW + 2u * (uint32_t)j) =
            (_Float16)emb[tok * E + j];
    }
    __syncthreads();

    if (tid < 256) __builtin_amdgcn_s_setprio(1);

    // ---- 3-stage chunked pipeline, one barrier per phase ----
    // phase p: osc1 chunk p (EB[p&1] -> ZB[p&1]); mm: coalesced gather chunk p+1
    // -> EB[(p+1)&1], MFMA chunk p-1 (ZB -> HB); osc2 chunk p-2 (HB[p&1]).
    for (int p = 0; p <= NC + 1; ++p) {
        if (tid < 128) {
            if (p < NC) {
                const uint32_t q = (uint32_t)(p & 1);
                const char* eb = smem + EBB + q * EBUF + 2u * (uint32_t)jc;
                char* zbase = smem + ZBB + q * ZBUF + 4u * (uint32_t)tid;
                // 2-deep u ring: chain-independent reads prefetched ahead
                float u0 = DTS * (float)(*(const _Float16*)(eb + 0u * EROW));
                float u1 = DTS * (float)(*(const _Float16*)(eb + 1u * EROW));
#pragma unroll 4
                for (int t = 0; t < TC; ++t) {
                    float u2 = 0.f;
                    if (t + 2 < TC)
                        u2 = DTS * (float)(*(const _Float16*)(eb + (uint32_t)(t + 2) * EROW));
                    eul5p(v1, dom1, u0);
                    if (act1)
                        *(h2_t*)(zbase + (uint32_t)t * ZROW) = cvt2h(v1[0], v1[1]);
                    u0 = u1; u1 = u2;
                }
            }
        } else if (tid < 256) {
            if (p >= 2) {
                const uint32_t q = (uint32_t)(p & 1);   // chunk p-2 parity
                const char* hbase = smem + HBB + q * HBUF + (uint32_t)j2c * HROW;
                const int s = j2c & 7;
                f16x8 e0 = *(const f16x8*)(hbase + ((0 ^ s) << 4));
                f16x8 e1 = *(const f16x8*)(hbase + ((1 ^ s) << 4));
                for (int gg = 0; gg < 8; ++gg) {
                    f16x8 e2 = e1;
                    if (gg + 2 < 8) e2 = *(const f16x8*)(hbase + (((gg + 2) ^ s) << 4));
#pragma unroll
                    for (int i = 0; i < 8; ++i)
                        eul5p(v2, dom2, DTS * (float)e0[i]);
                    e0 = e1; e1 = e2;
                }
            }
        } else {
            // A) coalesced emb gather for chunk p+1: wave mw owns rows mw*16..+15.
            //    lanes = feature j (consecutive) -> ~3 transactions/load vs 64.
            float rv0[16], rv1[16];
            const bool edo = (p + 1 < NC);
            int tokv = 0;
            if (edo) {
                tokv = xa[(p + 1) * TC + mw * 16 + (lane & 15)];
#pragma unroll
                for (int r = 0; r < 16; ++r) {
                    int tok = __builtin_amdgcn_readlane(tokv, r);
                    const float* ep = emb + (size_t)tok * E;
                    rv0[r] = ep[lane];
                    rv1[r] = ep[64 + ((lane < 36) ? lane : 35)];
                }
            }
            // B) 32x32x16 MFMA chunk p-1: C[64t x 100j] = z[64x224] * w1'[224x100]
            if (p >= 1 && p <= NC) {
                const uint32_t qm = (uint32_t)((p - 1) & 1);
                const char* zb = smem + ZBB + qm * ZBUF;
                const uint32_t arow = (uint32_t)(mh * 32 + (lane & 31)) * ZROW
                                      + 16u * (uint32_t)(lane >> 5);
                f32x16 acc0 = (f32x16)0.f, acc1 = (f32x16)0.f;
#pragma unroll
                for (int ks = 0; ks < 14; ++ks) {
                    f16x8 af = *(const f16x8*)(zb + arow + 32u * ks);
                    f16x8 bf0 = *(const f16x8*)(smem + brow[0] + 32u * ks);
                    acc0 = __builtin_amdgcn_mfma_f32_32x32x16_f16(af, bf0, acc0, 0, 0, 0);
                    f16x8 bf1 = *(const f16x8*)(smem + brow[1] + 32u * ks);
                    acc1 = __builtin_amdgcn_mfma_f32_32x32x16_f16(af, bf1, acc1, 0, 0, 0);
                }
                // C-write (col=lane&31, row=(reg&3)+8*(reg>>2)+4*(lane>>5))
                char* hb = smem + HBB + qm * HBUF;
#pragma unroll
                for (int nt = 0; nt < 2; ++nt) {
                    const int j = np * 64 + nt * 32 + (lane & 31);
                    if (j < U) {
#pragma unroll
                        for (int g = 0; g < 4; ++g) {
                            const int tb = mh * 32 + 8 * g + 4 * (lane >> 5);
                            f16x4 hv;
#pragma unroll
                            for (int r = 0; r < 4; ++r) {
                                float vv = (nt == 0) ? acc0[4 * g + r] : acc1[4 * g + r];
                                hv[r] = (_Float16)fmaxf(vv + b1r[nt], 0.f);
                            }
                            uint32_t off = (uint32_t)j * HROW
                                + (uint32_t)(((((tb >> 3) ^ (j & 7))) << 4) + ((2 * tb) & 15));
                            *(f16x4*)(hb + off) = hv;
                        }
                    }
                }
            }
            // C) writeback gathered emb -> EB t-major (row base + 2*lane: conflict-free)
            if (edo) {
                const uint32_t qe = (uint32_t)((p + 1) & 1);
                char* eb = smem + EBB + qe * EBUF;
#pragma unroll
                for (int r = 0; r < 16; ++r) {
                    char* rowp = eb + (uint32_t)(mw * 16 + r) * EROW;
                    *(_Float16*)(rowp + 2u * (uint32_t)lane) = (_Float16)rv0[r];
                    if (lane < 36)
                        *(_Float16*)(rowp + 2u * (uint32_t)(64 + lane)) = (_Float16)rv1[r];
                }
            }
        }
        __syncthreads();
    }

    if (tid < 256) __builtin_amdgcn_s_setprio(0);

    // ---- epilogue (scratch overlaid on dead EB region) ----
    float* zf2 = (float*)(smem + EBB);           // [2][104]
    float* pb  = (float*)(smem + EBB + 832u);    // [2][104]
    float* h2s = (float*)(smem + EBB + 1664u);   // [104]
    float* h3s = (float*)(smem + EBB + 2080u);   // [32]

    if (tid >= 128 && tid < 256) {
        const int j = tid - 128;
        if (j < U) { zf2[j] = v2[0]; zf2[104 + j] = v2[1]; }
    }
    __syncthreads();

    if (tid >= 256 && tid < 456) {
        const int e = tid - 256;
        const int h = e / 100, jq = e - 100 * (e / 100);
        float acc2 = 0.f;
#pragma unroll 4
        for (int kk = 0; kk < 100; ++kk)
            acc2 = fmaf(zf2[104 * h + kk], w2[(100 * h + kk) * U + jq], acc2);
        pb[104 * h + jq] = acc2;
    }
    __syncthreads();

    if (tid < U) h2s[tid] = fmaxf(pb[tid] + pb[104 + tid] + b2[tid], 0.f);
    __syncthreads();

    if (tid < P) {
        float acc = bp[tid];
#pragma unroll 4
        for (int j = 0; j < U; ++j) acc = fmaf(h2s[j], wp[j * P + tid], acc);
        h3s[tid] = tanhf(acc);
    }
    __syncthreads();

    if (tid < C) {
        float acc = bh[tid];
#pragma unroll
        for (int pp = 0; pp < P; ++pp) acc = fmaf(h3s[pp], wh[pp * C + tid], acc);
        out[b * C + tid] = acc;
    }
}
} // namespace

extern "C" void kernel_launch(void* const* d_in, const int* in_sizes, int n_in,
                              void* d_out, int out_size, void* d_ws, size_t ws_size,
                              hipStream_t stream) {
    const int* xi        = (const int*)d_in[0];
    const float* emb     = (const float*)d_in[1];
    const float* omega1  = (const float*)d_in[2];
    const float* omega2  = (const float*)d_in[3];
    const float* w1      = (const float*)d_in[4];
    const float* b1      = (const float*)d_in[5];
    const float* w2      = (const float*)d_in[6];
    const float* b2      = (const float*)d_in[7];
    const float* wp      = (const float*)d_in[8];
    const float* bp      = (const float*)d_in[9];
    const float* wh      = (const float*)d_in[10];
    const float* bh      = (const float*)d_in[11];
    float* out           = (float*)d_out;

    hipLaunchKernelGGL(donn_kernel, dim3(BATCH), dim3(512), 0, stream,
                       xi, emb, omega1, omega2, w1, b1, w2, b2, wp, bp, wh, bh, out);
}

// Round 11
// 119.667 us; speedup vs baseline: 1.1836x; 1.1836x over previous
//
#include <hip/hip_runtime.h>
#include <cmath>

namespace {
constexpr int T = 1024, BATCH = 128, U = 100, E = 100, P = 20, C = 2;
constexpr int TC = 64, NC = 16;          // chunk size, number of chunks
constexpr float DT = 0.001f, SCALE = 0.2f, MU = 1.0f;
constexpr float DTS = DT * SCALE;

// ---- LDS arena ----
// WL [100 j][464 B]   f16 w1, k'-interleaved (k'=2k | 2(k-U)+1), pads [400,464)=0
// ZB [2][64 t][464 B] f16 z (x_j,y_j)@4j, pads zero           (MFMA A operand)
// EB [2][100 j][128 B] f16 u, [unit][time] rows, chunk-XOR-swizzled
// HB [2][100 j][128 B] f16 h1, [unit][time] rows, chunk-XOR-swizzled
// XA [1024] int tokens (whole sequence, loaded once)
constexpr uint32_t WROW = 464u, ZROW = 464u, EROW = 128u, HROW = 128u;
constexpr uint32_t WLB = 0u;
constexpr uint32_t ZBB = 46400u, ZBUF = 29696u;
constexpr uint32_t EBB = 105792u, EBUF = 12800u;
constexpr uint32_t HBB = 131392u, HBUF = 12800u;
constexpr uint32_t XAB = 156992u;
constexpr uint32_t ARENA = 161088u;      // <= 163840

typedef _Float16 f16x8 __attribute__((ext_vector_type(8)));
typedef _Float16 f16x4 __attribute__((ext_vector_type(4)));
typedef float f32x16 __attribute__((ext_vector_type(16)));
typedef float f32x2 __attribute__((ext_vector_type(2)));
typedef _Float16 h2_t __attribute__((ext_vector_type(2)));

// packed Euler bank: 5 substeps, (x,y) in one f32x2, v_pk_fma for the vector ops.
// dom = DT*omega; ax = DT*SCALE*drive. 5 VALU insts/substep, chain depth 4.
__device__ __forceinline__ void eul5p(f32x2& v, float dom, float ax) {
    constexpr float c0 = 1.0f + DT * MU;
    const f32x2 dd = {-dom, dom};
    const f32x2 aa = {ax, 0.f};
#pragma unroll
    for (int s = 0; s < 5; ++s) {
        float r2 = fmaf(v[1], v[1], v[0] * v[0]);
        float sc = fmaf(-DT, r2, c0);
        f32x2 vyx = __builtin_shufflevector(v, v, 1, 0);
        f32x2 w = __builtin_elementwise_fma(vyx, dd, aa);
        f32x2 scv = {sc, sc};
        v = __builtin_elementwise_fma(v, scv, w);
    }
}

__device__ __forceinline__ h2_t cvt2h(float a, float b) {
    auto r = __builtin_amdgcn_cvt_pkrtz(a, b);
    return __builtin_bit_cast(h2_t, r);
}

__launch_bounds__(512, 1)
__global__ void donn_kernel(const int* __restrict__ xg,
                            const float* __restrict__ emb,
                            const float* __restrict__ omega1,
                            const float* __restrict__ omega2,
                            const float* __restrict__ w1,
                            const float* __restrict__ b1,
                            const float* __restrict__ w2,
                            const float* __restrict__ b2,
                            const float* __restrict__ wp,
                            const float* __restrict__ bp,
                            const float* __restrict__ wh,
                            const float* __restrict__ bh,
                            float* __restrict__ out)
{
    const int b = blockIdx.x;
    const int tid = threadIdx.x;

    __shared__ __align__(16) char smem[ARENA];
    int* xa = (int*)(smem + XAB);

    // ---- per-role persistent state ----
    f32x2 v1 = {0.f, 0.f}, v2 = {0.f, 0.f};
    float dom1 = 0.f, dom2 = 0.f;
    int jc = 0, j2c = 0;
    bool act1 = false;
    int lane = 0, mh = 0, np = 0, mw = 0;
    float b1r[2] = {0.f, 0.f};
    uint32_t brow[2] = {0u, 0u};

    if (tid < 128) {                       // osc1: unit j = tid (j<100 active)
        jc = (tid < U) ? tid : (U - 1);
        act1 = tid < U;
        dom1 = DT * omega1[jc];
    } else if (tid < 256) {                // osc2: unit j = tid-128
        const int j2 = tid - 128;
        j2c = (j2 < U) ? j2 : (U - 1);
        dom2 = DT * omega2[j2c];
    } else {                               // mm: 4 waves, 32x32x16 MFMA + gather
        mw = (tid >> 6) - 4;               // 0..3
        lane = tid & 63;
        mh = mw >> 1;                      // t-half: rows [mh*32, mh*32+32)
        np = mw & 1;                       // n-pair: j = np*64 + nt*32 + (lane&31)
#pragma unroll
        for (int nt = 0; nt < 2; ++nt) {
            int j = np * 64 + nt * 32 + (lane & 31);
            int jj = (j < U) ? j : (U - 1);
            b1r[nt] = b1[jj];
            brow[nt] = WLB + (uint32_t)jj * WROW + 16u * (uint32_t)(lane >> 5);
        }
    }

    // ---- prologue ----
    for (int i = tid; i < T; i += 512) xa[i] = xg[b * T + i];   // whole token seq
    for (int idx = tid; idx < 200 * 100; idx += 512) {          // w1 -> WL
        int k = idx / 100, j = idx - 100 * k;
        int kp = (k < U) ? (2 * k) : (2 * (k - U) + 1);
        *(_Float16*)(smem + WLB + (uint32_t)j * WROW + 2u * (uint32_t)kp) = (_Float16)w1[k * U + j];
    }
    for (int idx = tid; idx < 100 * 16; idx += 512) {           // WL pads [400,464)
        int row = idx >> 4, wd = idx & 15;
        *(float*)(smem + WLB + (uint32_t)row * WROW + 400u + 4u * (uint32_t)wd) = 0.f;
    }
    for (int idx = tid; idx < 128 * 16; idx += 512) {           // ZB pads [400,464)
        int zr = idx >> 4, wd = idx & 15;
        uint32_t base = ZBB + (uint32_t)(zr >> 6) * ZBUF + (uint32_t)(zr & 63) * ZROW;
        *(float*)(smem + base + 400u + 4u * (uint32_t)wd) = 0.f;
    }
    __syncthreads();
    for (int idx = tid; idx < 100 * TC; idx += 512) {           // EB[0] = chunk 0
        int j = idx >> 6, t = idx & 63;
        int tok = xa[t];
        uint32_t off = EBB + (uint32_t)j * EROW
                     + (uint32_t)(((((t >> 3) ^ (j & 7))) << 4) + 2 * (t & 7));
        *(_Float16*)(smem + off) = (_Float16)emb[tok * E + j];
    }
    __syncthreads();

    if (tid < 256) __builtin_amdgcn_s_setprio(1);

    // ---- 3-stage chunked pipeline, one barrier per phase ----
    // phase p: osc1 chunk p (EB[p&1] -> ZB[p&1]); mm: gather chunk p+1 -> EB[(p+1)&1],
    // MFMA chunk p-1 (ZB[(p-1)&1] -> HB[(p-1)&1]); osc2 chunk p-2 (HB[p&1]).
    for (int p = 0; p <= NC + 1; ++p) {
        if (tid < 128) {
            if (p < NC) {
                const uint32_t q = (uint32_t)(p & 1);
                const char* ebase = smem + EBB + q * EBUF + (uint32_t)jc * EROW;
                char* zbase = smem + ZBB + q * ZBUF + 4u * (uint32_t)tid;
                const int s = jc & 7;
                f16x8 e0 = *(const f16x8*)(ebase + ((0 ^ s) << 4));
                f16x8 e1 = *(const f16x8*)(ebase + ((1 ^ s) << 4));
                for (int gg = 0; gg < 8; ++gg) {
                    f16x8 e2 = e1;
                    if (gg + 2 < 8) e2 = *(const f16x8*)(ebase + (((gg + 2) ^ s) << 4));
                    char* zt = zbase + (uint32_t)(8 * gg) * ZROW;
#pragma unroll
                    for (int i = 0; i < 8; ++i) {
                        eul5p(v1, dom1, DTS * (float)e0[i]);
                        if (act1) {
                            h2_t zz = cvt2h(v1[0], v1[1]);
                            *(h2_t*)(zt + (uint32_t)i * ZROW) = zz;
                        }
                    }
                    e0 = e1; e1 = e2;
                }
            }
        } else if (tid < 256) {
            if (p >= 2) {
                const uint32_t q = (uint32_t)(p & 1);   // chunk p-2 parity
                const char* hbase = smem + HBB + q * HBUF + (uint32_t)j2c * HROW;
                const int s = j2c & 7;
                f16x8 e0 = *(const f16x8*)(hbase + ((0 ^ s) << 4));
                f16x8 e1 = *(const f16x8*)(hbase + ((1 ^ s) << 4));
                for (int gg = 0; gg < 8; ++gg) {
                    f16x8 e2 = e1;
                    if (gg + 2 < 8) e2 = *(const f16x8*)(hbase + (((gg + 2) ^ s) << 4));
#pragma unroll
                    for (int i = 0; i < 8; ++i)
                        eul5p(v2, dom2, DTS * (float)e0[i]);
                    e0 = e1; e1 = e2;
                }
            }
        } else {
            // A) issue emb gather for chunk p+1 (token from LDS, 25 imm-offset loads)
            float er[25];
            const bool edo = (p + 1 < NC);
            if (edo) {
                int tok = xa[(p + 1) * TC + lane];      // lane == timestep
                const float* ep = emb + (size_t)tok * E;
#pragma unroll
                for (int i = 0; i < 25; ++i) er[i] = ep[mw * 25 + i];
            }
            // B) 32x32x16 MFMA chunk p-1: C[64t x 100j] = z[64x224] * w1'[224x100]
            if (p >= 1 && p <= NC) {
                const uint32_t qm = (uint32_t)((p - 1) & 1);
                const char* zb = smem + ZBB + qm * ZBUF;
                const uint32_t arow = (uint32_t)(mh * 32 + (lane & 31)) * ZROW
                                      + 16u * (uint32_t)(lane >> 5);
                f32x16 acc0 = (f32x16)0.f, acc1 = (f32x16)0.f;
#pragma unroll
                for (int ks = 0; ks < 14; ++ks) {
                    f16x8 af = *(const f16x8*)(zb + arow + 32u * ks);
                    f16x8 bf0 = *(const f16x8*)(smem + brow[0] + 32u * ks);
                    acc0 = __builtin_amdgcn_mfma_f32_32x32x16_f16(af, bf0, acc0, 0, 0, 0);
                    f16x8 bf1 = *(const f16x8*)(smem + brow[1] + 32u * ks);
                    acc1 = __builtin_amdgcn_mfma_f32_32x32x16_f16(af, bf1, acc1, 0, 0, 0);
                }
                // C-write (col=lane&31, row=(reg&3)+8*(reg>>2)+4*(lane>>5))
                char* hb = smem + HBB + qm * HBUF;
#pragma unroll
                for (int nt = 0; nt < 2; ++nt) {
                    const int j = np * 64 + nt * 32 + (lane & 31);
                    if (j < U) {
#pragma unroll
                        for (int g = 0; g < 4; ++g) {
                            const int tb = mh * 32 + 8 * g + 4 * (lane >> 5);
                            f16x4 hv;
#pragma unroll
                            for (int r = 0; r < 4; ++r) {
                                float vv = (nt == 0) ? acc0[4 * g + r] : acc1[4 * g + r];
                                hv[r] = (_Float16)fmaxf(vv + b1r[nt], 0.f);
                            }
                            uint32_t off = (uint32_t)j * HROW
                                + (uint32_t)(((((tb >> 3) ^ (j & 7))) << 4) + ((2 * tb) & 15));
                            *(f16x4*)(hb + off) = hv;
                        }
                    }
                }
            }
            // C) write back gathered emb (vmcnt waits land here, after MFMA)
            if (edo) {
                const uint32_t qe = (uint32_t)((p + 1) & 1);
                char* eb = smem + EBB + qe * EBUF;
#pragma unroll
                for (int i = 0; i < 25; ++i) {
                    int jrow = mw * 25 + i;
                    uint32_t off = (uint32_t)jrow * EROW
                        + (uint32_t)(((((lane >> 3) ^ (jrow & 7))) << 4) + 2 * (lane & 7));
                    *(_Float16*)(eb + off) = (_Float16)er[i];
                }
            }
        }
        __syncthreads();
    }

    if (tid < 256) __builtin_amdgcn_s_setprio(0);

    // ---- epilogue (scratch overlaid on dead EB region) ----
    float* zf2 = (float*)(smem + EBB);           // [2][104]
    float* pb  = (float*)(smem + EBB + 832u);    // [2][104]
    float* h2s = (float*)(smem + EBB + 1664u);   // [104]
    float* h3s = (float*)(smem + EBB + 2080u);   // [32]

    if (tid >= 128 && tid < 256) {
        const int j = tid - 128;
        if (j < U) { zf2[j] = v2[0]; zf2[104 + j] = v2[1]; }
    }
    __syncthreads();

    if (tid >= 256 && tid < 456) {
        const int e = tid - 256;
        const int h = e / 100, jq = e - 100 * (e / 100);
        float acc2 = 0.f;
#pragma unroll 4
        for (int kk = 0; kk < 100; ++kk)
            acc2 = fmaf(zf2[104 * h + kk], w2[(100 * h + kk) * U + jq], acc2);
        pb[104 * h + jq] = acc2;
    }
    __syncthreads();

    if (tid < U) h2s[tid] = fmaxf(pb[tid] + pb[104 + tid] + b2[tid], 0.f);
    __syncthreads();

    if (tid < P) {
        float acc = bp[tid];
#pragma unroll 4
        for (int j = 0; j < U; ++j) acc = fmaf(h2s[j], wp[j * P + tid], acc);
        h3s[tid] = tanhf(acc);
    }
    __syncthreads();

    if (tid < C) {
        float acc = bh[tid];
#pragma unroll
        for (int pp = 0; pp < P; ++pp) acc = fmaf(h3s[pp], wh[pp * C + tid], acc);
        out[b * C + tid] = acc;
    }
}
} // namespace

extern "C" void kernel_launch(void* const* d_in, const int* in_sizes, int n_in,
                              void* d_out, int out_size, void* d_ws, size_t ws_size,
                              hipStream_t stream) {
    const int* xi        = (const int*)d_in[0];
    const float* emb     = (const float*)d_in[1];
    const float* omega1  = (const float*)d_in[2];
    const float* omega2  = (const float*)d_in[3];
    const float* w1      = (const float*)d_in[4];
    const float* b1      = (const float*)d_in[5];
    const float* w2      = (const float*)d_in[6];
    const float* b2      = (const float*)d_in[7];
    const float* wp      = (const float*)d_in[8];
    const float* bp      = (const float*)d_in[9];
    const float* wh      = (const float*)d_in[10];
    const float* bh      = (const float*)d_in[11];
    float* out           = (float*)d_out;

    hipLaunchKernelGGL(donn_kernel, dim3(BATCH), dim3(512), 0, stream,
                       xi, emb, omega1, omega2, w1, b1, w2, b2, wp, bp, wh, bh, out);
}